// Round 6
// baseline (414.159 us; speedup 1.0000x reference)
//
#include <hip/hip_runtime.h>
#include <hip/hip_bf16.h>

// ---------------------------------------------------------------------------
// Fused attention head. B=4, S=4096, D_IN=1024, D=128. bf16 MFMA 16x16x32.
// prep_weights -> qkv_proj (streaming GEMM, V transposed) -> attn_fwd
// attn_fwd: 8-wave blocks, intra-block s-split (wave w owns s in [w*512,+512)),
// private per-wave K-strip LDS (no loop barriers), V frags direct from L2,
// block-end (o,m,l) merge via LDS.  No global split partials.
// ---------------------------------------------------------------------------

typedef __attribute__((ext_vector_type(8))) short v8s;   // 8 x bf16
typedef __attribute__((ext_vector_type(4))) float v4f;   // MFMA C/D frag
typedef __attribute__((ext_vector_type(2))) unsigned int v2u;
typedef __attribute__((ext_vector_type(4))) int v4i;     // 16B staging chunk

#define SEQ   4096
#define DIN   1024
#define DH    128
#define NBAT  4

// f32 -> bf16 round-to-nearest-even
__device__ __forceinline__ unsigned short f2bf(float f) {
  unsigned u = __float_as_uint(f);
  u += 0x7fffu + ((u >> 16) & 1u);
  return (unsigned short)(u >> 16);
}

// --------------------------------------------------------------------------
// Kernel 0: Wt[z][c][k] = bf16(W_z[k][c]);  [3][128][1024]
// --------------------------------------------------------------------------
__global__ void prep_weights(const float* __restrict__ Wq, const float* __restrict__ Wk,
                             const float* __restrict__ Wv, short* __restrict__ Wt) {
  int idx = blockIdx.x * 256 + threadIdx.x;
  int z = idx >> 17;
  int e = idx & 131071;                              // k*128 + c
  int k = e >> 7, c = e & 127;
  const float* W = (z == 0) ? Wq : (z == 1) ? Wk : Wv;
  Wt[z * 131072 + c * 1024 + k] = (short)f2bf(W[e]);
}

// --------------------------------------------------------------------------
// Kernel 1: Out[16384,128] = X[16384,1024] @ W + b.  blockIdx.y = z.
// 16 rows/wave, 64 rows/block -> grid (256,3) = 768 blocks (3 waves/SIMD).
// X f32 direct (cvt in reg), W B-frags from L2-resident Wt[c][k].
// --------------------------------------------------------------------------
__global__ __launch_bounds__(256) void qkv_proj(
    const float* __restrict__ Xq, const float* __restrict__ Xk, const float* __restrict__ Xv,
    const float* __restrict__ bq, const float* __restrict__ bk, const float* __restrict__ bv,
    const short* __restrict__ Wt,
    short* __restrict__ Qb, short* __restrict__ Kb, short* __restrict__ Vtb) {
  const int z = blockIdx.y;
  const float* X    = (z == 0) ? Xq : (z == 1) ? Xk : Xv;
  const float* bias = (z == 0) ? bq : (z == 1) ? bk : bv;
  const short* W    = Wt + z * 131072;

  const int tid = threadIdx.x, wid = tid >> 6, lane = tid & 63;
  const int lg = lane >> 4, li = lane & 15;
  const int r0 = blockIdx.x * 64 + wid * 16;

  const float* xp0 = X + (size_t)(r0 + li) * DIN + lg * 8;

  v4f acc[8];
#pragma unroll
  for (int ni = 0; ni < 8; ++ni) { acc[ni][0]=0.f; acc[ni][1]=0.f; acc[ni][2]=0.f; acc[ni][3]=0.f; }

#pragma unroll 2
  for (int ks = 0; ks < 32; ++ks) {
    v4f x0 = *(const v4f*)(xp0 + ks * 32);
    v4f x1 = *(const v4f*)(xp0 + ks * 32 + 4);
    v8s a0;
    a0[0]=(short)f2bf(x0[0]); a0[1]=(short)f2bf(x0[1]); a0[2]=(short)f2bf(x0[2]); a0[3]=(short)f2bf(x0[3]);
    a0[4]=(short)f2bf(x1[0]); a0[5]=(short)f2bf(x1[1]); a0[6]=(short)f2bf(x1[2]); a0[7]=(short)f2bf(x1[3]);
#pragma unroll
    for (int ni = 0; ni < 8; ++ni) {
      v8s b = *(const v8s*)&W[(ni * 16 + li) * DIN + ks * 32 + lg * 8];
      acc[ni] = __builtin_amdgcn_mfma_f32_16x16x32_bf16(a0, b, acc[ni], 0, 0, 0);
    }
  }

  // epilogue: C/D col = ni*16+li, rows = r0 + lg*4 + r
#pragma unroll
  for (int ni = 0; ni < 8; ++ni) {
    const int col = ni * 16 + li;
    const float bb = bias[col];
    const int row0 = r0 + lg * 4;
    v4f r = acc[ni];
    if (z < 2) {
      short* Out = (z == 0) ? Qb : Kb;
#pragma unroll
      for (int rr = 0; rr < 4; ++rr)
        Out[(size_t)(row0 + rr) * DH + col] = (short)f2bf(r[rr] + bb);
    } else {
      const int bat = row0 >> 12;
      const int s0  = row0 & 4095;
      unsigned lo = (unsigned)f2bf(r[0] + bb) | ((unsigned)f2bf(r[1] + bb) << 16);
      unsigned hi = (unsigned)f2bf(r[2] + bb) | ((unsigned)f2bf(r[3] + bb) << 16);
      v2u pk; pk[0] = lo; pk[1] = hi;
      *(v2u*)&Vtb[(size_t)bat * (DH * SEQ) + (size_t)col * SEQ + s0] = pk;  // Vt[b][d][s]
    }
  }
}

// --------------------------------------------------------------------------
// Kernel 2: flash attention, 512 threads (8 waves), 32 q/block.
// Wave w owns s in [w*512, (w+1)*512), processed as 16 strips of 32 s.
// Private LDS per wave: K strip [32][128] swizzled (8 KB) + P [32 q][32 s]
// (2 KB).  No barriers in the loop.  V frags read direct from global (L2).
// Block-end merge of 8 per-wave partials via LDS.
// --------------------------------------------------------------------------
__global__ __launch_bounds__(512, 2) void attn_fwd(
    const short* __restrict__ Qb, const short* __restrict__ Kb,
    const short* __restrict__ Vtb, float* __restrict__ out) {
  // loop phase: wave w uses bytes [w*10240, w*10240+10240)  (80 KB)
  // merge phase: o[w] = floats [w*4096, +4096) (128 KB); m at 131072+, l at 132096+
  __shared__ __align__(16) char lds[133120];

  const int tid = threadIdx.x, w = tid >> 6, lane = tid & 63;
  const int lg = lane >> 4, li = lane & 15;
  const int b = blockIdx.y;
  const int q0 = blockIdx.x * 32;
  const float kSc = 0.08838834764831845f * 1.4426950408889634f;  // 1/sqrt(128)*log2(e)

  char* Klds = lds + w * 10240;
  char* Plds = Klds + 8192;

  const short* Q  = Qb + ((size_t)b * SEQ + q0) * DH;
  const char* Kp  = (const char*)(Kb + ((size_t)b * SEQ + w * 512) * DH);
  const char* Vpc = (const char*)Vtb + ((size_t)b * DH * SEQ + w * 512) * 2;

  // Q frags (B-operand of swapped QK^T): lane holds Q[qh*16+li][dc*32+lg*8..]
  v8s qf[4][2];
#pragma unroll
  for (int dc = 0; dc < 4; ++dc)
#pragma unroll
    for (int qh = 0; qh < 2; ++qh)
      qf[dc][qh] = *(const v8s*)&Q[(size_t)(qh * 16 + li) * DH + dc * 32 + lg * 8];

  v4f o[8][2];
#pragma unroll
  for (int dt = 0; dt < 8; ++dt)
#pragma unroll
    for (int qh = 0; qh < 2; ++qh) { o[dt][qh][0]=0.f; o[dt][qh][1]=0.f; o[dt][qh][2]=0.f; o[dt][qh][3]=0.f; }
  float m[2] = {-1e30f, -1e30f}, l[2] = {0.f, 0.f};

  // K staging: 32 rows x 256 B per strip; 2 lanes per row (128 B each)
  const int krow = lane >> 1, khalf = lane & 1;
  v4i kreg[8];
  auto loadK = [&](int st) {
    const char* p = Kp + (size_t)st * 8192 + krow * 256 + khalf * 128;
#pragma unroll
    for (int j = 0; j < 8; ++j) kreg[j] = *(const v4i*)(p + j * 16);
  };
  auto writeK = [&]() {
#pragma unroll
    for (int j = 0; j < 8; ++j) {
      int c = krow * 256 + khalf * 128 + j * 16;
      *(v4i*)(Klds + (c ^ ((krow & 7) << 4))) = kreg[j];
    }
  };

  loadK(0);
  writeK();

#pragma unroll 1
  for (int t = 0; t < 16; ++t) {
    if (t < 15) loadK(t + 1);                 // issue next-strip loads early (T14)

    // ---- S^T = K @ Q^T over this 32-s strip
    v4f stt[2][2];
#pragma unroll
    for (int tt = 0; tt < 2; ++tt)
#pragma unroll
      for (int qh = 0; qh < 2; ++qh) { stt[tt][qh][0]=0.f; stt[tt][qh][1]=0.f; stt[tt][qh][2]=0.f; stt[tt][qh][3]=0.f; }
#pragma unroll
    for (int tt = 0; tt < 2; ++tt)
#pragma unroll
      for (int dc = 0; dc < 4; ++dc) {
        v8s kf = *(const v8s*)(Klds + ((((tt * 16 + li) * 256) + dc * 64 + lg * 16) ^ ((li & 7) << 4)));
        stt[tt][0] = __builtin_amdgcn_mfma_f32_16x16x32_bf16(kf, qf[dc][0], stt[tt][0], 0, 0, 0);
        stt[tt][1] = __builtin_amdgcn_mfma_f32_16x16x32_bf16(kf, qf[dc][1], stt[tt][1], 0, 0, 0);
      }

    // ---- V fragments for this strip, direct from global (L2-hot)
    v8s vf[8];
#pragma unroll
    for (int dt = 0; dt < 8; ++dt)
      vf[dt] = *(const v8s*)(Vpc + (size_t)(dt * 16 + li) * 8192 + (size_t)t * 64 + lg * 16);

    // ---- online softmax (lane owns q = qh*16 + li)
    float fac[2];
#pragma unroll
    for (int qh = 0; qh < 2; ++qh) {
      float mx = m[qh];
#pragma unroll
      for (int tt = 0; tt < 2; ++tt)
        mx = fmaxf(mx, fmaxf(fmaxf(stt[tt][qh][0], stt[tt][qh][1]), fmaxf(stt[tt][qh][2], stt[tt][qh][3])));
      mx = fmaxf(mx, __shfl_xor(mx, 16));
      mx = fmaxf(mx, __shfl_xor(mx, 32));
      fac[qh] = exp2f((m[qh] - mx) * kSc);
      m[qh] = mx;
      float ps = 0.f;
#pragma unroll
      for (int tt = 0; tt < 2; ++tt) {
        float p0 = exp2f((stt[tt][qh][0] - mx) * kSc);
        float p1 = exp2f((stt[tt][qh][1] - mx) * kSc);
        float p2 = exp2f((stt[tt][qh][2] - mx) * kSc);
        float p3 = exp2f((stt[tt][qh][3] - mx) * kSc);
        ps += (p0 + p1) + (p2 + p3);
        v2u pk;
        pk[0] = (unsigned)f2bf(p0) | ((unsigned)f2bf(p1) << 16);
        pk[1] = (unsigned)f2bf(p2) | ((unsigned)f2bf(p3) << 16);
        // P row = q (64 B), byte = s*2;  s = tt*16 + lg*4 + r
        *(v2u*)(Plds + ((((qh * 16 + li) * 64) + tt * 32 + lg * 8) ^ ((li & 3) << 4))) = pk;
      }
      ps += __shfl_xor(ps, 16);
      ps += __shfl_xor(ps, 32);
      l[qh] = l[qh] * fac[qh] + ps;
    }

    if (t < 15) writeK();                     // private LDS: no barrier needed

    // ---- rescale O (row q = qh*16 + lg*4 + r)
    float facr[2][4];
#pragma unroll
    for (int qh = 0; qh < 2; ++qh)
#pragma unroll
      for (int r = 0; r < 4; ++r) facr[qh][r] = __shfl(fac[qh], lg * 4 + r);
#pragma unroll
    for (int dt = 0; dt < 8; ++dt)
#pragma unroll
      for (int qh = 0; qh < 2; ++qh) {
        o[dt][qh][0] *= facr[qh][0]; o[dt][qh][1] *= facr[qh][1];
        o[dt][qh][2] *= facr[qh][2]; o[dt][qh][3] *= facr[qh][3];
      }

    // ---- PV: O[q][d] += P[q][s] V[s][d]   (k = 32-s strip, one chunk)
    v8s pf[2];
#pragma unroll
    for (int qh = 0; qh < 2; ++qh)
      pf[qh] = *(const v8s*)(Plds + ((((qh * 16 + li) * 64) + lg * 16) ^ ((li & 3) << 4)));
#pragma unroll
    for (int dt = 0; dt < 8; ++dt) {
      o[dt][0] = __builtin_amdgcn_mfma_f32_16x16x32_bf16(pf[0], vf[dt], o[dt][0], 0, 0, 0);
      o[dt][1] = __builtin_amdgcn_mfma_f32_16x16x32_bf16(pf[1], vf[dt], o[dt][1], 0, 0, 0);
    }
  }

  // ---- block-end merge of the 8 per-wave partials
  float* olds = (float*)lds;                   // [w][q 32][d 128] f32
  float* mlds = (float*)(lds + 131072);        // [w][q 32]
  float* llds = (float*)(lds + 132096);        // [w][q 32]
  __syncthreads();                             // all waves done with loop LDS
#pragma unroll
  for (int dt = 0; dt < 8; ++dt)
#pragma unroll
    for (int qh = 0; qh < 2; ++qh)
#pragma unroll
      for (int r = 0; r < 4; ++r)
        olds[w * 4096 + (qh * 16 + lg * 4 + r) * 128 + dt * 16 + li] = o[dt][qh][r];
  if (lg == 0) {
#pragma unroll
    for (int qh = 0; qh < 2; ++qh) {
      mlds[w * 32 + qh * 16 + li] = m[qh];
      llds[w * 32 + qh * 16 + li] = l[qh];
    }
  }
  __syncthreads();

  const int q = tid >> 4, d0 = (tid & 15) * 8;
  float M = -1e30f;
#pragma unroll
  for (int ww = 0; ww < 8; ++ww) M = fmaxf(M, mlds[ww * 32 + q]);
  float den = 0.f;
  float av[8] = {0.f, 0.f, 0.f, 0.f, 0.f, 0.f, 0.f, 0.f};
#pragma unroll
  for (int ww = 0; ww < 8; ++ww) {
    float wt = exp2f((mlds[ww * 32 + q] - M) * kSc);
    den += wt * llds[ww * 32 + q];
    const float* op = &olds[ww * 4096 + q * 128 + d0];
#pragma unroll
    for (int j = 0; j < 8; ++j) av[j] += wt * op[j];
  }
  const float inv = 1.f / den;
  float* dst = out + ((size_t)b * SEQ + q0 + q) * DH + d0;
#pragma unroll
  for (int j = 0; j < 8; ++j) dst[j] = av[j] * inv;
}

// --------------------------------------------------------------------------
extern "C" void kernel_launch(void* const* d_in, const int* in_sizes, int n_in,
                              void* d_out, int out_size, void* d_ws, size_t ws_size,
                              hipStream_t stream) {
  const float* query = (const float*)d_in[0];
  const float* key   = (const float*)d_in[1];
  const float* value = (const float*)d_in[2];
  const float* Wq    = (const float*)d_in[3];
  const float* bqp   = (const float*)d_in[4];
  const float* Wk    = (const float*)d_in[5];
  const float* bkp   = (const float*)d_in[6];
  const float* Wv    = (const float*)d_in[7];
  const float* bvp   = (const float*)d_in[8];

  char* ws = (char*)d_ws;
  const size_t WT_SZ  = (size_t)3 * 128 * 1024 * 2;       //   786432
  const size_t QKV_SZ = (size_t)NBAT * SEQ * DH * 2;      //  4194304
  short* Wt  = (short*)ws;
  short* Qb  = (short*)(ws + WT_SZ);
  short* Kb  = (short*)(ws + WT_SZ + QKV_SZ);
  short* Vtb = (short*)(ws + WT_SZ + 2 * QKV_SZ);         // total 13.4 MB

  prep_weights<<<1536, 256, 0, stream>>>(Wq, Wk, Wv, Wt);
  qkv_proj<<<dim3(256, 3), 256, 0, stream>>>(query, key, value, bqp, bkp, bvp,
                                             Wt, Qb, Kb, Vtb);
  attn_fwd<<<dim3(128, NBAT), 512, 0, stream>>>(Qb, Kb, Vtb, (float*)d_out);
}